// Round 5
// baseline (373.738 us; speedup 1.0000x reference)
//
#include <hip/hip_runtime.h>
#include <hip/hip_bf16.h>

// Problem dims (fixed by setup_inputs): B=4, S=2048, DIN=4096, DOUT=4096, GS=32
#define DIN   4096
#define DOUT  4096
#define MROWS 8192            // B*S
#define GSIZE 32
#define NGPR  (DIN / GSIZE)   // groups per row = 128
#define NG_ACT (MROWS * NGPR) // 1048576
#define NG_W   (DOUT * NGPR)  // 524288

typedef __bf16 bf16_t;
typedef __attribute__((ext_vector_type(8))) __bf16 bf16x8;
typedef __attribute__((ext_vector_type(4))) float f32x4;

typedef const __attribute__((address_space(1))) void* gptr_t;
typedef __attribute__((address_space(3))) void* lptr_t;

// floor(log2(max(a,1))) grid rounding to the FP4 E2M1 set {0,±0.5,1,1.5,2,3,4,6}
__device__ __forceinline__ float fp4_round(float y) {
  float a  = __builtin_fabsf(y);
  float am = fmaxf(a, 1.0f);
  int   e  = (int)((__float_as_uint(am) >> 23) & 255u) - 127;  // floor(log2(max(a,1)))
  float step = __uint_as_float((unsigned)(e - 1 + 127) << 23); // 2^(e-1): 0.5, 1, 2
  float q = rintf(a / step) * step;  // RNE, matches jnp.round
  q = fminf(q, 6.0f);
  return copysignf(q, y);
}

// ---------------- activation quant: one thread per group of 32 ----------------
__global__ __launch_bounds__(256) void act_quant(const float* __restrict__ x,
                                                 bf16_t* __restrict__ xq,
                                                 float* __restrict__ exps_out) {
  int g = blockIdx.x * 256 + threadIdx.x;
  const float4* xp = reinterpret_cast<const float4*>(x) + (size_t)g * 8;
  float v[32];
  float amax = 0.f;
#pragma unroll
  for (int i = 0; i < 8; ++i) {
    float4 t = xp[i];
    v[4*i+0] = t.x; v[4*i+1] = t.y; v[4*i+2] = t.z; v[4*i+3] = t.w;
    amax = fmaxf(amax, fmaxf(fmaxf(__builtin_fabsf(t.x), __builtin_fabsf(t.y)),
                             fmaxf(__builtin_fabsf(t.z), __builtin_fabsf(t.w))));
  }
  float exps = 0.f;
  if (amax > 0.f) {
    float am = fmaxf(amax, 1e-30f);
    exps = (float)((int)((__float_as_uint(am) >> 23) & 255u) - 129);  // floor(log2)-2
  }
  float scale = __uint_as_float((unsigned)((int)exps + 127) << 23);   // 2^exps (exact)
  float inv   = __uint_as_float((unsigned)(127 - (int)exps) << 23);   // 2^-exps (exact)
  bf16x8 hv[4];
#pragma unroll
  for (int i = 0; i < 32; ++i) {
    float q = fp4_round(v[i] * inv) * scale;  // exact: pow2 scaling both ways
    hv[i >> 3][i & 7] = (bf16_t)q;            // exact in bf16 (<=2 mantissa bits * 2^e)
  }
  bf16x8* dst = reinterpret_cast<bf16x8*>(xq + (size_t)g * 32);
#pragma unroll
  for (int i = 0; i < 4; ++i) dst[i] = hv[i];
  exps_out[g] = exps;
}

// ---------------- weight quant with (1+eps_eff) scale ----------------
__global__ __launch_bounds__(256) void w_quant(const float* __restrict__ w,
                                               const float* __restrict__ eps,
                                               const float* __restrict__ adv,
                                               bf16_t* __restrict__ wq,
                                               float* __restrict__ eps_eff_out,
                                               float* __restrict__ w_exps_out) {
  int g = blockIdx.x * 256 + threadIdx.x;
  float ee = eps[g] + adv[g];
  eps_eff_out[g] = ee;
  const float4* wp = reinterpret_cast<const float4*>(w) + (size_t)g * 8;
  float v[32];
  float amax = 0.f;
#pragma unroll
  for (int i = 0; i < 8; ++i) {
    float4 t = wp[i];
    v[4*i+0] = t.x; v[4*i+1] = t.y; v[4*i+2] = t.z; v[4*i+3] = t.w;
    amax = fmaxf(amax, fmaxf(fmaxf(__builtin_fabsf(t.x), __builtin_fabsf(t.y)),
                             fmaxf(__builtin_fabsf(t.z), __builtin_fabsf(t.w))));
  }
  float exps = 0.f;
  if (amax > 0.f) {
    float am = fmaxf(amax, 1e-30f);
    exps = (float)((int)((__float_as_uint(am) >> 23) & 255u) - 129);
  }
  w_exps_out[g] = exps;
  float p2   = __uint_as_float((unsigned)((int)exps + 127) << 23);  // 2^exps
  float scale = p2 * (1.0f + ee);                                   // matches reference order
  bf16x8 hv[4];
#pragma unroll
  for (int i = 0; i < 32; ++i) {
    float q = fp4_round(v[i] / scale) * scale;  // IEEE div, matches reference
    hv[i >> 3][i & 7] = (bf16_t)q;              // only bf16-rounding error source
  }
  bf16x8* dst = reinterpret_cast<bf16x8*>(wq + (size_t)g * 32);
#pragma unroll
  for (int i = 0; i < 4; ++i) dst[i] = hv[i];
}

// ---------------- bf16 GEMM: C[M,N] = A[M,K] * B[N,K]^T + bias ----------------
// 256x256 tile, BK=64, 8 waves (2Mx4N), 512 thr, 128 KiB LDS double-buffer.
// m201-faithful 4-phase K-loop:
//   phase = { ds-reads | 1 half-tile stage } -> s_barrier -> lgkmcnt(0)
//           -> setprio(1) 16xMFMA setprio(0) -> s_barrier
// CRITICAL: builtin s_barrier + clobber-free waitcnt asm. An asm barrier with
// a "memory" clobber makes the backend drain vmcnt(0)+lgkmcnt(0) at EVERY
// barrier, nullifying the counted-vmcnt pipeline (r4 post-mortem: 2400 stall
// cyc/K-tile). Phase containment of ds_reads is guaranteed by may-alias with
// the global_load_lds LDS writes; data waits by compiler dependency tracking.
// Quadrants: Q0=mlo*nlo(ph1), Q1=mhi*nlo(ph2), Q2=mlo*nhi(ph3), Q3=mhi*nhi(ph4)
//   -> A(buf) free after ph2, B(buf) free after ph3.
// Stage stream (iter j, p=j&1): ph1 B-h0(j+1)->p^1, ph2 B-h1(j+1)->p^1,
//   ph3 A-h0(j+2)->p, ph4 A-h1(j+2)->p; end-of-iter vmcnt(4) retires tile j+1
//   (12 outstanding -> 4: A(j+2) stays in flight). Never vmcnt(0) in steady state.
#define NT 64   // K-tiles

__global__ __launch_bounds__(512, 2) void gemm_bt(const bf16_t* __restrict__ A,
                                                  const bf16_t* __restrict__ B,
                                                  const float* __restrict__ bias,
                                                  float* __restrict__ C) {
  __shared__ bf16_t sA[2 * 16384];
  __shared__ bf16_t sB[2 * 16384];
  const int tid  = threadIdx.x;
  const int wave = tid >> 6;   // 0..7
  const int lane = tid & 63;

  // T1: bijective XCD swizzle (512 blocks, 512 % 8 == 0)
  const int swz = (blockIdx.x & 7) * 64 + (blockIdx.x >> 3);
  const int tm0 = (swz >> 4) * 256;   // 32 M-tiles
  const int tn0 = (swz & 15) * 256;   // 16 N-tiles

  const int wr = wave >> 2;   // 0..1 : M-half (128 rows)
  const int wc = wave & 3;    // 0..3 : N-quarter (64 cols)

  // ---- half-tile staging: each wave stages 16 rows of each 128-row half ----
  // (2 x global_load_lds of 8 rows each; linear LDS dest, T2 pre-swizzled src)
  const int lrow8 = lane >> 3;                    // 0..7
  const int csw   = ((lane & 7) ^ lrow8) * 8;     // swizzled global k-chunk
  const bf16_t* gA = A + (size_t)(tm0 + wave * 16 + lrow8) * DIN + csw;
  const bf16_t* gB = B + (size_t)(tn0 + wave * 16 + lrow8) * DIN + csw;
  const int stg0 = wave * 1024;  // elems: (wave*16 rows) * 64 cols

#define STGH(sM, gM, d, h, kt) do {                                          \
    const bf16_t* g_ = (gM) + (size_t)(h) * 128 * DIN + (size_t)(kt) * 64;   \
    __builtin_amdgcn_global_load_lds((gptr_t)g_,                             \
        (lptr_t)((sM) + (d) * 16384 + (h) * 8192 + stg0), 16, 0, 0);         \
    __builtin_amdgcn_global_load_lds((gptr_t)(g_ + 8 * DIN),                 \
        (lptr_t)((sM) + (d) * 16384 + (h) * 8192 + stg0 + 512), 16, 0, 0);   \
  } while (0)

  // ---- fragment read offsets (bytes): phys = row*128 + 16*((kk*4+(l>>4)) ^ (l&7))
  const int arow_b = (wr * 128 + (lane & 15)) * 128;
  const int brow_b = (wc * 64 + (lane & 15)) * 128;
  const int slot0  = (((lane >> 4) ^ (lane & 7)) << 4);   // kk=0; kk=1 -> ^0x40

  f32x4 acc[8][4] = {};

  // ---- prologue: stage tile 0 (A,B) + A(1); wait tile 0; 1.5 tiles in flight ----
  STGH(sA, gA, 0, 0, 0); STGH(sA, gA, 0, 1, 0);
  STGH(sB, gB, 0, 0, 0); STGH(sB, gB, 0, 1, 0);
  STGH(sA, gA, 1, 0, 1); STGH(sA, gA, 1, 1, 1);
  asm volatile("s_waitcnt vmcnt(4)");       // tile 0's 8 loads retired
  __builtin_amdgcn_s_barrier();

  for (int j = 0; j < NT; ++j) {
    const int p = j & 1;
    const char* bufA = (const char*)sA + p * 32768;
    const char* bufB = (const char*)sB + p * 32768;
    bf16x8 a0[4][2], a1[4][2], bn[4][2];

    // ======== phase 1: ds a-lo(8)+b-lo(4); stage B-h0(j+1); Q0 = mlo x nlo ========
#pragma unroll
    for (int m = 0; m < 4; ++m)
#pragma unroll
      for (int kk = 0; kk < 2; ++kk)
        a0[m][kk] = *reinterpret_cast<const bf16x8*>(bufA + arow_b + m * 2048 + (slot0 ^ (kk << 6)));
#pragma unroll
    for (int t = 0; t < 2; ++t)
#pragma unroll
      for (int kk = 0; kk < 2; ++kk)
        bn[t][kk] = *reinterpret_cast<const bf16x8*>(bufB + brow_b + t * 2048 + (slot0 ^ (kk << 6)));
    if (j + 1 < NT) STGH(sB, gB, p ^ 1, 0, j + 1);   // B(p^1) free since iter j-1 ph3
    asm volatile("s_waitcnt lgkmcnt(8)");
    __builtin_amdgcn_s_barrier();
    asm volatile("s_waitcnt lgkmcnt(0)");
    __builtin_amdgcn_s_setprio(1);
#pragma unroll
    for (int kk = 0; kk < 2; ++kk)
#pragma unroll
      for (int t = 0; t < 2; ++t)
#pragma unroll
        for (int m = 0; m < 4; ++m)
          acc[m][t] = __builtin_amdgcn_mfma_f32_16x16x32_bf16(a0[m][kk], bn[t][kk], acc[m][t], 0, 0, 0);
    __builtin_amdgcn_s_setprio(0);
    __builtin_amdgcn_s_barrier();

    // ======== phase 2: ds a-hi(8); stage B-h1(j+1); Q1 = mhi x nlo ========
#pragma unroll
    for (int m = 0; m < 4; ++m)
#pragma unroll
      for (int kk = 0; kk < 2; ++kk)
        a1[m][kk] = *reinterpret_cast<const bf16x8*>(bufA + arow_b + (4 + m) * 2048 + (slot0 ^ (kk << 6)));
    if (j + 1 < NT) STGH(sB, gB, p ^ 1, 1, j + 1);
    __builtin_amdgcn_s_barrier();
    asm volatile("s_waitcnt lgkmcnt(0)");
    __builtin_amdgcn_s_setprio(1);
#pragma unroll
    for (int kk = 0; kk < 2; ++kk)
#pragma unroll
      for (int t = 0; t < 2; ++t)
#pragma unroll
        for (int m = 0; m < 4; ++m)
          acc[4 + m][t] = __builtin_amdgcn_mfma_f32_16x16x32_bf16(a1[m][kk], bn[t][kk], acc[4 + m][t], 0, 0, 0);
    __builtin_amdgcn_s_setprio(0);
    __builtin_amdgcn_s_barrier();

    // ======== phase 3: ds b-hi(4); stage A-h0(j+2); Q2 = mlo x nhi ========
#pragma unroll
    for (int t = 2; t < 4; ++t)
#pragma unroll
      for (int kk = 0; kk < 2; ++kk)
        bn[t][kk] = *reinterpret_cast<const bf16x8*>(bufB + brow_b + t * 2048 + (slot0 ^ (kk << 6)));
    if (j + 2 < NT) STGH(sA, gA, p, 0, j + 2);       // A(p) tile-j fully read (ph1+ph2)
    __builtin_amdgcn_s_barrier();
    asm volatile("s_waitcnt lgkmcnt(0)");
    __builtin_amdgcn_s_setprio(1);
#pragma unroll
    for (int kk = 0; kk < 2; ++kk)
#pragma unroll
      for (int t = 0; t < 2; ++t)
#pragma unroll
        for (int m = 0; m < 4; ++m)
          acc[m][2 + t] = __builtin_amdgcn_mfma_f32_16x16x32_bf16(a0[m][kk], bn[2 + t][kk], acc[m][2 + t], 0, 0, 0);
    __builtin_amdgcn_s_setprio(0);
    __builtin_amdgcn_s_barrier();

    // ======== phase 4: stage A-h1(j+2); Q3 = mhi x nhi; counted vmcnt ========
    if (j + 2 < NT) STGH(sA, gA, p, 1, j + 2);
    __builtin_amdgcn_s_barrier();
    asm volatile("s_waitcnt lgkmcnt(0)");
    __builtin_amdgcn_s_setprio(1);
#pragma unroll
    for (int kk = 0; kk < 2; ++kk)
#pragma unroll
      for (int t = 0; t < 2; ++t)
#pragma unroll
        for (int m = 0; m < 4; ++m)
          acc[4 + m][2 + t] = __builtin_amdgcn_mfma_f32_16x16x32_bf16(a1[m][kk], bn[2 + t][kk], acc[4 + m][2 + t], 0, 0, 0);
    __builtin_amdgcn_s_setprio(0);
    if (j < NT - 2) {
      asm volatile("s_waitcnt vmcnt(4)");   // tile j+1 landed; A(j+2) still in flight
    } else {
      asm volatile("s_waitcnt vmcnt(0)");   // tail drain
    }
    __builtin_amdgcn_s_barrier();
  }

  // ---- epilogue: D row=(lane>>4)*4+reg, col=lane&15 (m89-verified) ----
  const int r0 = tm0 + wr * 128 + ((lane >> 4) << 2);
  const int c0 = tn0 + wc * 64 + (lane & 15);
#pragma unroll
  for (int n = 0; n < 4; ++n) {
    float bv = bias[c0 + n * 16];
#pragma unroll
    for (int m = 0; m < 8; ++m) {
#pragma unroll
      for (int jj = 0; jj < 4; ++jj) {
        C[(size_t)(r0 + m * 16 + jj) * DOUT + c0 + n * 16] = acc[m][n][jj] + bv;
      }
    }
  }
#undef STGH
}

extern "C" void kernel_launch(void* const* d_in, const int* in_sizes, int n_in,
                              void* d_out, int out_size, void* d_ws, size_t ws_size,
                              hipStream_t stream) {
  const float* x    = (const float*)d_in[0];  // (4,2048,4096)
  const float* adv  = (const float*)d_in[1];  // (4096,128)
  const float* wfp  = (const float*)d_in[2];  // (4096,4096)
  const float* bias = (const float*)d_in[3];  // (4096,)
  const float* eps  = (const float*)d_in[4];  // (4096,128)

  float* out      = (float*)d_out;                    // 33554432
  float* eps_eff  = out + (size_t)MROWS * DOUT;       // 524288
  float* w_exps   = eps_eff + NG_W;                   // 524288
  float* act_exps = w_exps + NG_W;                    // 1048576

  bf16_t* xq = (bf16_t*)d_ws;                          // 67.1 MB
  bf16_t* wq = (bf16_t*)d_ws + (size_t)MROWS * DIN;    // +33.6 MB

  act_quant<<<NG_ACT / 256, 256, 0, stream>>>(x, xq, act_exps);
  w_quant<<<NG_W / 256, 256, 0, stream>>>(wfp, eps, adv, wq, eps_eff, w_exps);
  gemm_bt<<<dim3((MROWS / 256) * (DOUT / 256)), 512, 0, stream>>>(xq, wq, bias, out);
}

// Round 6
// 346.156 us; speedup vs baseline: 1.0797x; 1.0797x over previous
//
#include <hip/hip_runtime.h>
#include <hip/hip_bf16.h>

// Problem dims (fixed by setup_inputs): B=4, S=2048, DIN=4096, DOUT=4096, GS=32
#define DIN   4096
#define DOUT  4096
#define MROWS 8192            // B*S
#define GSIZE 32
#define NGPR  (DIN / GSIZE)   // groups per row = 128
#define NG_ACT (MROWS * NGPR) // 1048576
#define NG_W   (DOUT * NGPR)  // 524288

typedef __bf16 bf16_t;
typedef __attribute__((ext_vector_type(8))) __bf16 bf16x8;
typedef __attribute__((ext_vector_type(4))) float f32x4;

typedef const __attribute__((address_space(1))) void* gptr_t;
typedef __attribute__((address_space(3))) void* lptr_t;

// floor(log2(max(a,1))) grid rounding to the FP4 E2M1 set {0,±0.5,1,1.5,2,3,4,6}
__device__ __forceinline__ float fp4_round(float y) {
  float a  = __builtin_fabsf(y);
  float am = fmaxf(a, 1.0f);
  int   e  = (int)((__float_as_uint(am) >> 23) & 255u) - 127;  // floor(log2(max(a,1)))
  float step = __uint_as_float((unsigned)(e - 1 + 127) << 23); // 2^(e-1): 0.5, 1, 2
  float q = rintf(a / step) * step;  // RNE, matches jnp.round
  q = fminf(q, 6.0f);
  return copysignf(q, y);
}

// ---------------- activation quant: one thread per group of 32 ----------------
__global__ __launch_bounds__(256) void act_quant(const float* __restrict__ x,
                                                 bf16_t* __restrict__ xq,
                                                 float* __restrict__ exps_out) {
  int g = blockIdx.x * 256 + threadIdx.x;
  const float4* xp = reinterpret_cast<const float4*>(x) + (size_t)g * 8;
  float v[32];
  float amax = 0.f;
#pragma unroll
  for (int i = 0; i < 8; ++i) {
    float4 t = xp[i];
    v[4*i+0] = t.x; v[4*i+1] = t.y; v[4*i+2] = t.z; v[4*i+3] = t.w;
    amax = fmaxf(amax, fmaxf(fmaxf(__builtin_fabsf(t.x), __builtin_fabsf(t.y)),
                             fmaxf(__builtin_fabsf(t.z), __builtin_fabsf(t.w))));
  }
  float exps = 0.f;
  if (amax > 0.f) {
    float am = fmaxf(amax, 1e-30f);
    exps = (float)((int)((__float_as_uint(am) >> 23) & 255u) - 129);  // floor(log2)-2
  }
  float scale = __uint_as_float((unsigned)((int)exps + 127) << 23);   // 2^exps (exact)
  float inv   = __uint_as_float((unsigned)(127 - (int)exps) << 23);   // 2^-exps (exact)
  bf16x8 hv[4];
#pragma unroll
  for (int i = 0; i < 32; ++i) {
    float q = fp4_round(v[i] * inv) * scale;  // exact: pow2 scaling both ways
    hv[i >> 3][i & 7] = (bf16_t)q;            // exact in bf16 (<=2 mantissa bits * 2^e)
  }
  bf16x8* dst = reinterpret_cast<bf16x8*>(xq + (size_t)g * 32);
#pragma unroll
  for (int i = 0; i < 4; ++i) dst[i] = hv[i];
  exps_out[g] = exps;
}

// ---------------- weight quant with (1+eps_eff) scale ----------------
__global__ __launch_bounds__(256) void w_quant(const float* __restrict__ w,
                                               const float* __restrict__ eps,
                                               const float* __restrict__ adv,
                                               bf16_t* __restrict__ wq,
                                               float* __restrict__ eps_eff_out,
                                               float* __restrict__ w_exps_out) {
  int g = blockIdx.x * 256 + threadIdx.x;
  float ee = eps[g] + adv[g];
  eps_eff_out[g] = ee;
  const float4* wp = reinterpret_cast<const float4*>(w) + (size_t)g * 8;
  float v[32];
  float amax = 0.f;
#pragma unroll
  for (int i = 0; i < 8; ++i) {
    float4 t = wp[i];
    v[4*i+0] = t.x; v[4*i+1] = t.y; v[4*i+2] = t.z; v[4*i+3] = t.w;
    amax = fmaxf(amax, fmaxf(fmaxf(__builtin_fabsf(t.x), __builtin_fabsf(t.y)),
                             fmaxf(__builtin_fabsf(t.z), __builtin_fabsf(t.w))));
  }
  float exps = 0.f;
  if (amax > 0.f) {
    float am = fmaxf(amax, 1e-30f);
    exps = (float)((int)((__float_as_uint(am) >> 23) & 255u) - 129);
  }
  w_exps_out[g] = exps;
  float p2   = __uint_as_float((unsigned)((int)exps + 127) << 23);  // 2^exps
  float scale = p2 * (1.0f + ee);                                   // matches reference order
  bf16x8 hv[4];
#pragma unroll
  for (int i = 0; i < 32; ++i) {
    float q = fp4_round(v[i] / scale) * scale;  // IEEE div, matches reference
    hv[i >> 3][i & 7] = (bf16_t)q;              // only bf16-rounding error source
  }
  bf16x8* dst = reinterpret_cast<bf16x8*>(wq + (size_t)g * 32);
#pragma unroll
  for (int i = 0; i < 4; ++i) dst[i] = hv[i];
}

// ---------------- bf16 GEMM: C[M,N] = A[M,K] * B[N,K]^T + bias ----------------
// 256x256 tile, BK=64, 8 waves (2Mx4N), 512 thr, 128 KiB LDS double-buffer.
// r6 = r4's DEEP staging schedule + clobber-free builtin barriers (isolating
// experiment: r4 had asm "memory" barriers = possible forced vmcnt/lgkm drains;
// r5 had clean barriers but SHALLOW staging depth — regressed).
// Per K-tile (4 phases):
//   ph1: ds a-lo(8)+b-lo(4);                       Q0 = mlo x nlo
//   ph2: ds b-hi(4);                               Q1 = mlo x nhi  (B(p) free)
//   ph3: ds a-hi(8); stage B-h0,B-h1(j+2)->p;      Q2 = mhi x nlo  (A(p) free)
//   ph4: stage A-h0,A-h1(j+2)->p;                  Q3 = mhi x nhi
//   then vmcnt(8): tile j+1 (issued iter j-1, 4-6 phases ago ~ >1200cyc cover)
//   retired; tile j+2's 8 loads stay in flight. Never vmcnt(0) in steady state.
// Each phase: {reads|stage} -> s_barrier -> lgkmcnt(0) -> setprio(1) 16xMFMA
//   setprio(0) -> s_barrier.  All barriers = __builtin_amdgcn_s_barrier();
//   all waitcnt asm clobber-free (no forced drains).
#define NT 64   // K-tiles

__global__ __launch_bounds__(512, 2) void gemm_bt(const bf16_t* __restrict__ A,
                                                  const bf16_t* __restrict__ B,
                                                  const float* __restrict__ bias,
                                                  float* __restrict__ C) {
  __shared__ bf16_t sA[2 * 16384];
  __shared__ bf16_t sB[2 * 16384];
  const int tid  = threadIdx.x;
  const int wave = tid >> 6;   // 0..7
  const int lane = tid & 63;

  // T1: bijective XCD swizzle (512 blocks, 512 % 8 == 0)
  const int swz = (blockIdx.x & 7) * 64 + (blockIdx.x >> 3);
  const int tm0 = (swz >> 4) * 256;   // 32 M-tiles
  const int tn0 = (swz & 15) * 256;   // 16 N-tiles

  const int wr = wave >> 2;   // 0..1 : M-half (128 rows)
  const int wc = wave & 3;    // 0..3 : N-quarter (64 cols)

  // ---- half-tile staging: each wave stages 16 rows of each 128-row half ----
  // (2 x global_load_lds of 8 rows each; linear LDS dest, T2 pre-swizzled src)
  const int lrow8 = lane >> 3;                    // 0..7
  const int csw   = ((lane & 7) ^ lrow8) * 8;     // swizzled global k-chunk
  const bf16_t* gA = A + (size_t)(tm0 + wave * 16 + lrow8) * DIN + csw;
  const bf16_t* gB = B + (size_t)(tn0 + wave * 16 + lrow8) * DIN + csw;
  const int stg0 = wave * 1024;  // elems: (wave*16 rows) * 64 cols

#define STGH(sM, gM, d, h, kt) do {                                          \
    const bf16_t* g_ = (gM) + (size_t)(h) * 128 * DIN + (size_t)(kt) * 64;   \
    __builtin_amdgcn_global_load_lds((gptr_t)g_,                             \
        (lptr_t)((sM) + (d) * 16384 + (h) * 8192 + stg0), 16, 0, 0);         \
    __builtin_amdgcn_global_load_lds((gptr_t)(g_ + 8 * DIN),                 \
        (lptr_t)((sM) + (d) * 16384 + (h) * 8192 + stg0 + 512), 16, 0, 0);   \
  } while (0)

  // ---- fragment read offsets (bytes): phys = row*128 + 16*((kk*4+(l>>4)) ^ (l&7))
  const int arow_b = (wr * 128 + (lane & 15)) * 128;
  const int brow_b = (wc * 64 + (lane & 15)) * 128;
  const int slot0  = (((lane >> 4) ^ (lane & 7)) << 4);   // kk=0; kk=1 -> ^0x40

  f32x4 acc[8][4] = {};

  // ---- prologue: stage K-tiles 0 and 1 fully; wait for tile 0 ----
  STGH(sA, gA, 0, 0, 0); STGH(sA, gA, 0, 1, 0);
  STGH(sB, gB, 0, 0, 0); STGH(sB, gB, 0, 1, 0);
  STGH(sB, gB, 1, 0, 1); STGH(sB, gB, 1, 1, 1);
  STGH(sA, gA, 1, 0, 1); STGH(sA, gA, 1, 1, 1);
  asm volatile("s_waitcnt vmcnt(8)");       // tile 0's 8 loads retired
  __builtin_amdgcn_s_barrier();

  for (int j = 0; j < NT; ++j) {
    const int p = j & 1;
    const char* bufA = (const char*)sA + p * 32768;
    const char* bufB = (const char*)sB + p * 32768;
    bf16x8 a0[4][2], a1[4][2], bn[4][2];

    // ======== phase 1: ds a-lo(8)+b-lo(4); Q0 = mlo x nlo ========
#pragma unroll
    for (int m = 0; m < 4; ++m)
#pragma unroll
      for (int kk = 0; kk < 2; ++kk)
        a0[m][kk] = *reinterpret_cast<const bf16x8*>(bufA + arow_b + m * 2048 + (slot0 ^ (kk << 6)));
#pragma unroll
    for (int t = 0; t < 2; ++t)
#pragma unroll
      for (int kk = 0; kk < 2; ++kk)
        bn[t][kk] = *reinterpret_cast<const bf16x8*>(bufB + brow_b + t * 2048 + (slot0 ^ (kk << 6)));
    asm volatile("s_waitcnt lgkmcnt(8)");
    __builtin_amdgcn_s_barrier();
    asm volatile("s_waitcnt lgkmcnt(0)");
    __builtin_amdgcn_s_setprio(1);
#pragma unroll
    for (int kk = 0; kk < 2; ++kk)
#pragma unroll
      for (int t = 0; t < 2; ++t)
#pragma unroll
        for (int m = 0; m < 4; ++m)
          acc[m][t] = __builtin_amdgcn_mfma_f32_16x16x32_bf16(a0[m][kk], bn[t][kk], acc[m][t], 0, 0, 0);
    __builtin_amdgcn_s_setprio(0);
    __builtin_amdgcn_s_barrier();

    // ======== phase 2: ds b-hi(4); Q1 = mlo x nhi (reuses a0) ========
#pragma unroll
    for (int t = 2; t < 4; ++t)
#pragma unroll
      for (int kk = 0; kk < 2; ++kk)
        bn[t][kk] = *reinterpret_cast<const bf16x8*>(bufB + brow_b + t * 2048 + (slot0 ^ (kk << 6)));
    __builtin_amdgcn_s_barrier();
    asm volatile("s_waitcnt lgkmcnt(0)");
    __builtin_amdgcn_s_setprio(1);
#pragma unroll
    for (int kk = 0; kk < 2; ++kk)
#pragma unroll
      for (int t = 0; t < 2; ++t)
#pragma unroll
        for (int m = 0; m < 4; ++m)
          acc[m][2 + t] = __builtin_amdgcn_mfma_f32_16x16x32_bf16(a0[m][kk], bn[2 + t][kk], acc[m][2 + t], 0, 0, 0);
    __builtin_amdgcn_s_setprio(0);
    __builtin_amdgcn_s_barrier();

    // ======== phase 3: ds a-hi(8); stage B(j+2)->p; Q2 = mhi x nlo ========
    // B(p) of tile j fully read (ph1+ph2, all waves past ph2 barrier).
#pragma unroll
    for (int m = 0; m < 4; ++m)
#pragma unroll
      for (int kk = 0; kk < 2; ++kk)
        a1[m][kk] = *reinterpret_cast<const bf16x8*>(bufA + arow_b + (4 + m) * 2048 + (slot0 ^ (kk << 6)));
    if (j + 2 < NT) {
      STGH(sB, gB, p, 0, j + 2);
      STGH(sB, gB, p, 1, j + 2);
    }
    __builtin_amdgcn_s_barrier();
    asm volatile("s_waitcnt lgkmcnt(0)");
    __builtin_amdgcn_s_setprio(1);
#pragma unroll
    for (int kk = 0; kk < 2; ++kk)
#pragma unroll
      for (int t = 0; t < 2; ++t)
#pragma unroll
        for (int m = 0; m < 4; ++m)
          acc[4 + m][t] = __builtin_amdgcn_mfma_f32_16x16x32_bf16(a1[m][kk], bn[t][kk], acc[4 + m][t], 0, 0, 0);
    __builtin_amdgcn_s_setprio(0);
    __builtin_amdgcn_s_barrier();

    // ======== phase 4: stage A(j+2)->p; Q3 = mhi x nhi; counted vmcnt ========
    // A(p) of tile j fully read (ph1+ph3, all waves past ph3 barrier).
    if (j + 2 < NT) {
      STGH(sA, gA, p, 0, j + 2);
      STGH(sA, gA, p, 1, j + 2);
    }
    __builtin_amdgcn_s_barrier();
    __builtin_amdgcn_s_setprio(1);
#pragma unroll
    for (int kk = 0; kk < 2; ++kk)
#pragma unroll
      for (int t = 0; t < 2; ++t)
#pragma unroll
        for (int m = 0; m < 4; ++m)
          acc[4 + m][2 + t] = __builtin_amdgcn_mfma_f32_16x16x32_bf16(a1[m][kk], bn[2 + t][kk], acc[4 + m][2 + t], 0, 0, 0);
    __builtin_amdgcn_s_setprio(0);
    if (j < NT - 2) {
      asm volatile("s_waitcnt vmcnt(8)");   // tile j+1 landed; tile j+2 in flight
    } else {
      asm volatile("s_waitcnt vmcnt(0)");   // tail drain
    }
    __builtin_amdgcn_s_barrier();
  }

  // ---- epilogue: D row=(lane>>4)*4+reg, col=lane&15 (m89-verified) ----
  const int r0 = tm0 + wr * 128 + ((lane >> 4) << 2);
  const int c0 = tn0 + wc * 64 + (lane & 15);
#pragma unroll
  for (int n = 0; n < 4; ++n) {
    float bv = bias[c0 + n * 16];
#pragma unroll
    for (int m = 0; m < 8; ++m) {
#pragma unroll
      for (int jj = 0; jj < 4; ++jj) {
        C[(size_t)(r0 + m * 16 + jj) * DOUT + c0 + n * 16] = acc[m][n][jj] + bv;
      }
    }
  }
#undef STGH
}

extern "C" void kernel_launch(void* const* d_in, const int* in_sizes, int n_in,
                              void* d_out, int out_size, void* d_ws, size_t ws_size,
                              hipStream_t stream) {
  const float* x    = (const float*)d_in[0];  // (4,2048,4096)
  const float* adv  = (const float*)d_in[1];  // (4096,128)
  const float* wfp  = (const float*)d_in[2];  // (4096,4096)
  const float* bias = (const float*)d_in[3];  // (4096,)
  const float* eps  = (const float*)d_in[4];  // (4096,128)

  float* out      = (float*)d_out;                    // 33554432
  float* eps_eff  = out + (size_t)MROWS * DOUT;       // 524288
  float* w_exps   = eps_eff + NG_W;                   // 524288
  float* act_exps = w_exps + NG_W;                    // 1048576

  bf16_t* xq = (bf16_t*)d_ws;                          // 67.1 MB
  bf16_t* wq = (bf16_t*)d_ws + (size_t)MROWS * DIN;    // +33.6 MB

  act_quant<<<NG_ACT / 256, 256, 0, stream>>>(x, xq, act_exps);
  w_quant<<<NG_W / 256, 256, 0, stream>>>(wfp, eps, adv, wq, eps_eff, w_exps);
  gemm_bt<<<dim3((MROWS / 256) * (DOUT / 256)), 512, 0, stream>>>(xq, wq, bias, out);
}

// Round 7
// 338.029 us; speedup vs baseline: 1.1056x; 1.0240x over previous
//
#include <hip/hip_runtime.h>
#include <hip/hip_bf16.h>

// Problem dims (fixed by setup_inputs): B=4, S=2048, DIN=4096, DOUT=4096, GS=32
#define DIN   4096
#define DOUT  4096
#define MROWS 8192            // B*S
#define GSIZE 32
#define NGPR  (DIN / GSIZE)   // groups per row = 128
#define NG_ACT (MROWS * NGPR) // 1048576
#define NG_W   (DOUT * NGPR)  // 524288

typedef __bf16 bf16_t;
typedef __attribute__((ext_vector_type(8))) __bf16 bf16x8;
typedef __attribute__((ext_vector_type(4))) float f32x4;

typedef const __attribute__((address_space(1))) void* gptr_t;
typedef __attribute__((address_space(3))) void* lptr_t;

// floor(log2(max(a,1))) grid rounding to the FP4 E2M1 set {0,±0.5,1,1.5,2,3,4,6}
__device__ __forceinline__ float fp4_round(float y) {
  float a  = __builtin_fabsf(y);
  float am = fmaxf(a, 1.0f);
  int   e  = (int)((__float_as_uint(am) >> 23) & 255u) - 127;  // floor(log2(max(a,1)))
  float step = __uint_as_float((unsigned)(e - 1 + 127) << 23); // 2^(e-1): 0.5, 1, 2
  float q = rintf(a / step) * step;  // RNE, matches jnp.round
  q = fminf(q, 6.0f);
  return copysignf(q, y);
}

// ---------------- activation quant: one thread per group of 32 ----------------
__global__ __launch_bounds__(256) void act_quant(const float* __restrict__ x,
                                                 bf16_t* __restrict__ xq,
                                                 float* __restrict__ exps_out) {
  int g = blockIdx.x * 256 + threadIdx.x;
  const float4* xp = reinterpret_cast<const float4*>(x) + (size_t)g * 8;
  float v[32];
  float amax = 0.f;
#pragma unroll
  for (int i = 0; i < 8; ++i) {
    float4 t = xp[i];
    v[4*i+0] = t.x; v[4*i+1] = t.y; v[4*i+2] = t.z; v[4*i+3] = t.w;
    amax = fmaxf(amax, fmaxf(fmaxf(__builtin_fabsf(t.x), __builtin_fabsf(t.y)),
                             fmaxf(__builtin_fabsf(t.z), __builtin_fabsf(t.w))));
  }
  float exps = 0.f;
  if (amax > 0.f) {
    float am = fmaxf(amax, 1e-30f);
    exps = (float)((int)((__float_as_uint(am) >> 23) & 255u) - 129);  // floor(log2)-2
  }
  float scale = __uint_as_float((unsigned)((int)exps + 127) << 23);   // 2^exps (exact)
  float inv   = __uint_as_float((unsigned)(127 - (int)exps) << 23);   // 2^-exps (exact)
  bf16x8 hv[4];
#pragma unroll
  for (int i = 0; i < 32; ++i) {
    float q = fp4_round(v[i] * inv) * scale;  // exact: pow2 scaling both ways
    hv[i >> 3][i & 7] = (bf16_t)q;            // exact in bf16 (<=2 mantissa bits * 2^e)
  }
  bf16x8* dst = reinterpret_cast<bf16x8*>(xq + (size_t)g * 32);
#pragma unroll
  for (int i = 0; i < 4; ++i) dst[i] = hv[i];
  exps_out[g] = exps;
}

// ---------------- weight quant with (1+eps_eff) scale ----------------
__global__ __launch_bounds__(256) void w_quant(const float* __restrict__ w,
                                               const float* __restrict__ eps,
                                               const float* __restrict__ adv,
                                               bf16_t* __restrict__ wq,
                                               float* __restrict__ eps_eff_out,
                                               float* __restrict__ w_exps_out) {
  int g = blockIdx.x * 256 + threadIdx.x;
  float ee = eps[g] + adv[g];
  eps_eff_out[g] = ee;
  const float4* wp = reinterpret_cast<const float4*>(w) + (size_t)g * 8;
  float v[32];
  float amax = 0.f;
#pragma unroll
  for (int i = 0; i < 8; ++i) {
    float4 t = wp[i];
    v[4*i+0] = t.x; v[4*i+1] = t.y; v[4*i+2] = t.z; v[4*i+3] = t.w;
    amax = fmaxf(amax, fmaxf(fmaxf(__builtin_fabsf(t.x), __builtin_fabsf(t.y)),
                             fmaxf(__builtin_fabsf(t.z), __builtin_fabsf(t.w))));
  }
  float exps = 0.f;
  if (amax > 0.f) {
    float am = fmaxf(amax, 1e-30f);
    exps = (float)((int)((__float_as_uint(am) >> 23) & 255u) - 129);
  }
  w_exps_out[g] = exps;
  float p2   = __uint_as_float((unsigned)((int)exps + 127) << 23);  // 2^exps
  float scale = p2 * (1.0f + ee);                                   // matches reference order
  bf16x8 hv[4];
#pragma unroll
  for (int i = 0; i < 32; ++i) {
    float q = fp4_round(v[i] / scale) * scale;  // IEEE div, matches reference
    hv[i >> 3][i & 7] = (bf16_t)q;              // only bf16-rounding error source
  }
  bf16x8* dst = reinterpret_cast<bf16x8*>(wq + (size_t)g * 32);
#pragma unroll
  for (int i = 0; i < 4; ++i) dst[i] = hv[i];
}

// ---------------- bf16 GEMM: C[M,N] = A[M,K] * B[N,K]^T + bias ----------------
// 256x256 tile, BK=64, 8 waves (2Mx4N), 512 thr, 128 KiB LDS double-buffer.
// r7 = r6 with ALL explicit lgkmcnt asm removed (DERIVED WAITS, m232's missing
// piece): the compiler emits per-use counted lgkmcnt before each MFMA, so a
// wave starts its MFMA cluster as soon as ITS OWN operand reads return, while
// the LDS pipe still services other waves' reads -> read/MFMA cascade overlap
// instead of lockstep (r4-r6: explicit lgkm(0) forced every wave to wait for
// the whole phase's ~96 queued reads; modeled lockstep cost == measured 5756
// cyc/K-tile, MfmaUtil pinned 37%).
// Correctness unchanged: buffer-overwrite safety = barriers + LDS may-aliasing
// (global_load_lds writes vs ds_reads can't reorder); data deps = compiler.
// Per K-tile (4 phases):
//   ph1: ds a-lo(8)+b-lo(4);                  Q0 = mlo x nlo
//   ph2: ds b-hi(4);                          Q1 = mlo x nhi  (B(p) free)
//   ph3: ds a-hi(8); stage B(j+2)->p;         Q2 = mhi x nlo  (A(p) free)
//   ph4: stage A(j+2)->p;                     Q3 = mhi x nhi
//   then vmcnt(8): tile j+1 retired (issued 4-6 phases ago), j+2 in flight.
// Phase shape: {reads|stage} -> s_barrier -> setprio(1) 16xMFMA setprio(0)
//   -> s_barrier.  Builtin barriers, clobber-free counted vmcnt only.
#define NT 64   // K-tiles

__global__ __launch_bounds__(512, 2) void gemm_bt(const bf16_t* __restrict__ A,
                                                  const bf16_t* __restrict__ B,
                                                  const float* __restrict__ bias,
                                                  float* __restrict__ C) {
  __shared__ bf16_t sA[2 * 16384];
  __shared__ bf16_t sB[2 * 16384];
  const int tid  = threadIdx.x;
  const int wave = tid >> 6;   // 0..7
  const int lane = tid & 63;

  // T1: bijective XCD swizzle (512 blocks, 512 % 8 == 0)
  const int swz = (blockIdx.x & 7) * 64 + (blockIdx.x >> 3);
  const int tm0 = (swz >> 4) * 256;   // 32 M-tiles
  const int tn0 = (swz & 15) * 256;   // 16 N-tiles

  const int wr = wave >> 2;   // 0..1 : M-half (128 rows)
  const int wc = wave & 3;    // 0..3 : N-quarter (64 cols)

  // ---- half-tile staging: each wave stages 16 rows of each 128-row half ----
  // (2 x global_load_lds of 8 rows each; linear LDS dest, T2 pre-swizzled src)
  const int lrow8 = lane >> 3;                    // 0..7
  const int csw   = ((lane & 7) ^ lrow8) * 8;     // swizzled global k-chunk
  const bf16_t* gA = A + (size_t)(tm0 + wave * 16 + lrow8) * DIN + csw;
  const bf16_t* gB = B + (size_t)(tn0 + wave * 16 + lrow8) * DIN + csw;
  const int stg0 = wave * 1024;  // elems: (wave*16 rows) * 64 cols

#define STGH(sM, gM, d, h, kt) do {                                          \
    const bf16_t* g_ = (gM) + (size_t)(h) * 128 * DIN + (size_t)(kt) * 64;   \
    __builtin_amdgcn_global_load_lds((gptr_t)g_,                             \
        (lptr_t)((sM) + (d) * 16384 + (h) * 8192 + stg0), 16, 0, 0);         \
    __builtin_amdgcn_global_load_lds((gptr_t)(g_ + 8 * DIN),                 \
        (lptr_t)((sM) + (d) * 16384 + (h) * 8192 + stg0 + 512), 16, 0, 0);   \
  } while (0)

  // ---- fragment read offsets (bytes): phys = row*128 + 16*((kk*4+(l>>4)) ^ (l&7))
  const int arow_b = (wr * 128 + (lane & 15)) * 128;
  const int brow_b = (wc * 64 + (lane & 15)) * 128;
  const int slot0  = (((lane >> 4) ^ (lane & 7)) << 4);   // kk=0; kk=1 -> ^0x40

  f32x4 acc[8][4] = {};

  // ---- prologue: stage K-tiles 0 and 1 fully; wait for tile 0 ----
  STGH(sA, gA, 0, 0, 0); STGH(sA, gA, 0, 1, 0);
  STGH(sB, gB, 0, 0, 0); STGH(sB, gB, 0, 1, 0);
  STGH(sB, gB, 1, 0, 1); STGH(sB, gB, 1, 1, 1);
  STGH(sA, gA, 1, 0, 1); STGH(sA, gA, 1, 1, 1);
  asm volatile("s_waitcnt vmcnt(8)");       // tile 0's 8 loads retired
  __builtin_amdgcn_s_barrier();

  for (int j = 0; j < NT; ++j) {
    const int p = j & 1;
    const char* bufA = (const char*)sA + p * 32768;
    const char* bufB = (const char*)sB + p * 32768;
    bf16x8 a0[4][2], a1[4][2], bn[4][2];

    // ======== phase 1: ds a-lo(8)+b-lo(4); Q0 = mlo x nlo ========
#pragma unroll
    for (int m = 0; m < 4; ++m)
#pragma unroll
      for (int kk = 0; kk < 2; ++kk)
        a0[m][kk] = *reinterpret_cast<const bf16x8*>(bufA + arow_b + m * 2048 + (slot0 ^ (kk << 6)));
#pragma unroll
    for (int t = 0; t < 2; ++t)
#pragma unroll
      for (int kk = 0; kk < 2; ++kk)
        bn[t][kk] = *reinterpret_cast<const bf16x8*>(bufB + brow_b + t * 2048 + (slot0 ^ (kk << 6)));
    __builtin_amdgcn_s_barrier();
    __builtin_amdgcn_s_setprio(1);
#pragma unroll
    for (int kk = 0; kk < 2; ++kk)
#pragma unroll
      for (int t = 0; t < 2; ++t)
#pragma unroll
        for (int m = 0; m < 4; ++m)
          acc[m][t] = __builtin_amdgcn_mfma_f32_16x16x32_bf16(a0[m][kk], bn[t][kk], acc[m][t], 0, 0, 0);
    __builtin_amdgcn_s_setprio(0);
    __builtin_amdgcn_s_barrier();

    // ======== phase 2: ds b-hi(4); Q1 = mlo x nhi (reuses a0) ========
#pragma unroll
    for (int t = 2; t < 4; ++t)
#pragma unroll
      for (int kk = 0; kk < 2; ++kk)
        bn[t][kk] = *reinterpret_cast<const bf16x8*>(bufB + brow_b + t * 2048 + (slot0 ^ (kk << 6)));
    __builtin_amdgcn_s_barrier();
    __builtin_amdgcn_s_setprio(1);
#pragma unroll
    for (int kk = 0; kk < 2; ++kk)
#pragma unroll
      for (int t = 0; t < 2; ++t)
#pragma unroll
        for (int m = 0; m < 4; ++m)
          acc[m][2 + t] = __builtin_amdgcn_mfma_f32_16x16x32_bf16(a0[m][kk], bn[2 + t][kk], acc[m][2 + t], 0, 0, 0);
    __builtin_amdgcn_s_setprio(0);
    __builtin_amdgcn_s_barrier();

    // ======== phase 3: ds a-hi(8); stage B(j+2)->p; Q2 = mhi x nlo ========
    // B(p) of tile j fully read (ph1+ph2, all waves past ph2 barrier).
#pragma unroll
    for (int m = 0; m < 4; ++m)
#pragma unroll
      for (int kk = 0; kk < 2; ++kk)
        a1[m][kk] = *reinterpret_cast<const bf16x8*>(bufA + arow_b + (4 + m) * 2048 + (slot0 ^ (kk << 6)));
    if (j + 2 < NT) {
      STGH(sB, gB, p, 0, j + 2);
      STGH(sB, gB, p, 1, j + 2);
    }
    __builtin_amdgcn_s_barrier();
    __builtin_amdgcn_s_setprio(1);
#pragma unroll
    for (int kk = 0; kk < 2; ++kk)
#pragma unroll
      for (int t = 0; t < 2; ++t)
#pragma unroll
        for (int m = 0; m < 4; ++m)
          acc[4 + m][t] = __builtin_amdgcn_mfma_f32_16x16x32_bf16(a1[m][kk], bn[t][kk], acc[4 + m][t], 0, 0, 0);
    __builtin_amdgcn_s_setprio(0);
    __builtin_amdgcn_s_barrier();

    // ======== phase 4: stage A(j+2)->p; Q3 = mhi x nhi; counted vmcnt ========
    // A(p) of tile j fully read (ph1+ph3, all waves past ph3 barrier).
    if (j + 2 < NT) {
      STGH(sA, gA, p, 0, j + 2);
      STGH(sA, gA, p, 1, j + 2);
    }
    __builtin_amdgcn_s_barrier();
    __builtin_amdgcn_s_setprio(1);
#pragma unroll
    for (int kk = 0; kk < 2; ++kk)
#pragma unroll
      for (int t = 0; t < 2; ++t)
#pragma unroll
        for (int m = 0; m < 4; ++m)
          acc[4 + m][2 + t] = __builtin_amdgcn_mfma_f32_16x16x32_bf16(a1[m][kk], bn[2 + t][kk], acc[4 + m][2 + t], 0, 0, 0);
    __builtin_amdgcn_s_setprio(0);
    if (j < NT - 2) {
      asm volatile("s_waitcnt vmcnt(8)");   // tile j+1 landed; tile j+2 in flight
    } else {
      asm volatile("s_waitcnt vmcnt(0)");   // tail drain
    }
    __builtin_amdgcn_s_barrier();
  }

  // ---- epilogue: D row=(lane>>4)*4+reg, col=lane&15 (m89-verified) ----
  const int r0 = tm0 + wr * 128 + ((lane >> 4) << 2);
  const int c0 = tn0 + wc * 64 + (lane & 15);
#pragma unroll
  for (int n = 0; n < 4; ++n) {
    float bv = bias[c0 + n * 16];
#pragma unroll
    for (int m = 0; m < 8; ++m) {
#pragma unroll
      for (int jj = 0; jj < 4; ++jj) {
        C[(size_t)(r0 + m * 16 + jj) * DOUT + c0 + n * 16] = acc[m][n][jj] + bv;
      }
    }
  }
#undef STGH
}

extern "C" void kernel_launch(void* const* d_in, const int* in_sizes, int n_in,
                              void* d_out, int out_size, void* d_ws, size_t ws_size,
                              hipStream_t stream) {
  const float* x    = (const float*)d_in[0];  // (4,2048,4096)
  const float* adv  = (const float*)d_in[1];  // (4096,128)
  const float* wfp  = (const float*)d_in[2];  // (4096,4096)
  const float* bias = (const float*)d_in[3];  // (4096,)
  const float* eps  = (const float*)d_in[4];  // (4096,128)

  float* out      = (float*)d_out;                    // 33554432
  float* eps_eff  = out + (size_t)MROWS * DOUT;       // 524288
  float* w_exps   = eps_eff + NG_W;                   // 524288
  float* act_exps = w_exps + NG_W;                    // 1048576

  bf16_t* xq = (bf16_t*)d_ws;                          // 67.1 MB
  bf16_t* wq = (bf16_t*)d_ws + (size_t)MROWS * DIN;    // +33.6 MB

  act_quant<<<NG_ACT / 256, 256, 0, stream>>>(x, xq, act_exps);
  w_quant<<<NG_W / 256, 256, 0, stream>>>(wfp, eps, adv, wq, eps_eff, w_exps);
  gemm_bt<<<dim3((MROWS / 256) * (DOUT / 256)), 512, 0, stream>>>(xq, wq, bias, out);
}